// Round 9
// baseline (506.782 us; speedup 1.0000x reference)
//
#include <hip/hip_runtime.h>

typedef int      iv4 __attribute__((ext_vector_type(4)));
typedef unsigned uv4 __attribute__((ext_vector_type(4)));
typedef float    fv4 __attribute__((ext_vector_type(4)));

// ======== v9: 256-bucket sort + LDS-staged region gather + stream reduce ====
#define NREGS2  256               // x regions, 128 KB each at n_x = 2^23
#define RSH2    15                // region shift: ptr >> 15
#define REGW    (1 << RSH2)       // 32768 floats per region
#define BLK1    512
#define EPT1    16
#define CHUNK1  (BLK1 * EPT1)     // 8192 edges per pass-1 chunk
#define CPB     16                // chunks per reduce block
#define BLK2    1024
#define CAP     38400             // LDS segment-accumulator capacity (floats)

// ---- K1: sort each 8192-edge chunk by region; emit u16 sidecars ----
__global__ __launch_bounds__(BLK1) void sort_chunks2_kernel(
    const float* __restrict__ x,      // only for the (rare) sentinel path
    const int*   __restrict__ ptrs,
    const int*   __restrict__ csr,
    float*       __restrict__ out,
    unsigned short* __restrict__ wsp, // [n_edges] region-local ptr per bucket pos
    unsigned short* __restrict__ wss, // [n_edges] seg-local slot per bucket pos
    int*            __restrict__ wsb, // [n_chunks * (NREGS2+1)] per-chunk bounds
    long long eb)                     // edges per reduce block = CPB*CHUNK1
{
    __shared__ int      hist[NREGS2];
    __shared__ int      scan[NREGS2];
    __shared__ int      bounds[NREGS2 + 1];
    __shared__ unsigned packed[CHUNK1];   // 32 KB: (ptr_local16 << 16) | sl16

    const int c = blockIdx.x, tid = threadIdx.x;
    const long long base = (long long)c * CHUNK1;
    const int cb = (int)(base / eb);
    const int seg_base = csr[(long long)cb * eb];

    if (tid < NREGS2) hist[tid] = 0;
    __syncthreads();

    // coalesced index loads into registers
    int ps[EPT1], cs[EPT1];
    const iv4* p4 = reinterpret_cast<const iv4*>(ptrs + base);
    const iv4* s4 = reinterpret_cast<const iv4*>(csr + base);
    #pragma unroll
    for (int q = 0; q < EPT1 / 4; ++q) {
        iv4 p = __builtin_nontemporal_load(p4 + q * BLK1 + tid);
        ps[q*4+0] = p[0]; ps[q*4+1] = p[1]; ps[q*4+2] = p[2]; ps[q*4+3] = p[3];
    }
    #pragma unroll
    for (int q = 0; q < EPT1 / 4; ++q) {
        iv4 s = __builtin_nontemporal_load(s4 + q * BLK1 + tid);
        cs[q*4+0] = s[0]; cs[q*4+1] = s[1]; cs[q*4+2] = s[2]; cs[q*4+3] = s[3];
    }

    // histogram over 256 regions
    #pragma unroll
    for (int i = 0; i < EPT1; ++i) atomicAdd(&hist[ps[i] >> RSH2], 1);
    __syncthreads();

    // parallel Hillis-Steele inclusive scan -> bounds
    if (tid < NREGS2) scan[tid] = hist[tid];
    __syncthreads();
    for (int off = 1; off < NREGS2; off <<= 1) {
        int v = 0;
        if (tid < NREGS2) { v = scan[tid]; if (tid >= off) v += scan[tid - off]; }
        __syncthreads();
        if (tid < NREGS2) scan[tid] = v;
        __syncthreads();
    }
    if (tid < NREGS2) bounds[tid + 1] = scan[tid];
    if (tid == 0) bounds[0] = 0;
    __syncthreads();
    if (tid < NREGS2) hist[tid] = bounds[tid];     // scatter cursors
    __syncthreads();

    // rank + scatter into LDS (unstable OK: consumer accumulates by sl)
    #pragma unroll
    for (int i = 0; i < EPT1; ++i) {
        int pp = ps[i], ss = cs[i];
        int r  = pp >> RSH2;
        int sl = ss - seg_base;
        unsigned pk;
        if (sl >= 0xFFFF) {                        // pathological: direct add
            atomicAdd(out + ss, x[pp]);
            pk = (((unsigned)pp & (REGW - 1)) << 16) | 0xFFFFu;   // NOP sentinel
        } else {
            pk = (((unsigned)pp & (REGW - 1)) << 16) | (unsigned)sl;
        }
        int pos = atomicAdd(&hist[r], 1);
        packed[pos] = pk;
    }
    __syncthreads();

    // write-out: split u16 sidecars, 2 entries per u32 store (coalesced)
    {
        unsigned* p32 = reinterpret_cast<unsigned*>(wsp + base);
        unsigned* s32 = reinterpret_cast<unsigned*>(wss + base);
        for (int i = tid; i < CHUNK1 / 2; i += BLK1) {
            unsigned a = packed[2 * i], b = packed[2 * i + 1];
            __builtin_nontemporal_store((b & 0xFFFF0000u) | (a >> 16), p32 + i);
            __builtin_nontemporal_store((b << 16) | (a & 0xFFFFu),     s32 + i);
        }
    }
    for (int i = tid; i <= NREGS2; i += BLK1)
        wsb[(size_t)c * (NREGS2 + 1) + i] = bounds[i];
}

// ---- K2: block r stages x-region r in LDS, streams its slices ----
__global__ __launch_bounds__(BLK2) void region_gather_kernel(
    const float*          __restrict__ x,
    const unsigned short* __restrict__ wsp,
    float*                __restrict__ wsv,
    const int*            __restrict__ wsb,
    int n_chunks, int n_x)
{
    __shared__ float xr[REGW];                    // 128 KB

    const int r = blockIdx.x, tid = threadIdx.x;
    const int w = tid >> 6, lane = tid & 63;
    const long long rb = (long long)r << RSH2;

    // stage the region (coalesced float4); clamp against n_x
    {
        const fv4* xs = reinterpret_cast<const fv4*>(x + rb);
        fv4* xd = reinterpret_cast<fv4*>(xr);
        for (int i = tid; i < REGW / 4; i += BLK2)
            if (rb + (long long)i * 4 < n_x) xd[i] = xs[i];
    }
    __syncthreads();

    // wave w walks chunks w, w+16, ...: read slice entries, LDS-gather, write
    for (int c = w; c < n_chunks; c += CPB) {
        const int* bc = wsb + (size_t)c * (NREGS2 + 1) + r;
        const int lo = bc[0], hi = bc[1];          // uniform per wave
        const long long cbase = (long long)c * CHUNK1;
        for (int i = lo + lane; i < hi; i += 64) {
            unsigned short pl = wsp[cbase + i];
            wsv[cbase + i] = xr[pl];
        }
    }
}

// ---- K3: stream (sl, val) pairs, LDS accumulate, coalesced flush ----
__global__ __launch_bounds__(BLK2) void reduce_kernel(
    const int*            __restrict__ csr,
    float*                __restrict__ out,
    const unsigned short* __restrict__ wss,
    const float*          __restrict__ wsv,
    long long eb)
{
    __shared__ float accum[CAP];                  // 150 KB

    const int c = blockIdx.x, tid = threadIdx.x;
    const long long base = (long long)c * eb;

    for (int i = tid; i < CAP; i += BLK2) accum[i] = 0.f;
    const int seg_base = csr[base];
    const int seg_last = csr[base + eb - 1];
    __syncthreads();

    // flat stream: eb entries, 8 per thread-iteration
    const unsigned* s32 = reinterpret_cast<const unsigned*>(wss + base);
    const fv4*      v4  = reinterpret_cast<const fv4*>(wsv + base);
    const int iters = (int)(eb / (BLK2 * 8));
    for (int k = 0; k < iters; ++k) {
        const int idx = k * BLK2 + tid;            // 8-entry group index
        uv4 sv = __builtin_nontemporal_load(
                     reinterpret_cast<const uv4*>(s32) + idx);
        fv4 va = __builtin_nontemporal_load(v4 + 2 * idx);
        fv4 vb = __builtin_nontemporal_load(v4 + 2 * idx + 1);
        #pragma unroll
        for (int j = 0; j < 8; ++j) {
            int   sl = (int)((sv[j >> 1] >> (16 * (j & 1))) & 0xFFFFu);
            float vl = (j < 4) ? va[j] : vb[j - 4];
            if (sl == 0xFFFF) continue;            // handled in K1
            if (sl < CAP) atomicAdd(&accum[sl], vl);
            else          atomicAdd(out + seg_base + sl, vl);  // rare overflow
        }
    }
    __syncthreads();

    // flush: interior segments exclusive (csr sorted) -> plain stores;
    // the two block-boundary segments may be shared -> atomicAdd.
    const int range = seg_last - seg_base + 1;
    const int hi = range < CAP ? range : CAP;
    for (int i = tid; i < hi; i += BLK2) {
        float v = accum[i];
        if (i == 0 || i == range - 1) {
            if (v != 0.f) atomicAdd(out + seg_base + i, v);
        } else {
            out[seg_base + i] = v;
        }
    }
}

// =================== v7 fallback (128 regions, fused consume) ===============
#define NREGS   128
#define RSH     16

__global__ __launch_bounds__(BLK1) void sort_chunks_kernel(
    const float* __restrict__ x,
    const int*   __restrict__ ptrs,
    const int*   __restrict__ csr,
    float*       __restrict__ out,
    unsigned*    __restrict__ wse,
    int*         __restrict__ wsb,
    long long eb)
{
    __shared__ int      hist[NREGS];
    __shared__ int      bounds[NREGS + 1];
    __shared__ unsigned packed[CHUNK1];

    const int c = blockIdx.x, tid = threadIdx.x;
    const long long base = (long long)c * CHUNK1;
    const int cb = (int)(base / eb);
    const int seg_base = csr[(long long)cb * eb];

    if (tid < NREGS) hist[tid] = 0;
    __syncthreads();

    int ps[EPT1], cs[EPT1];
    const iv4* p4 = reinterpret_cast<const iv4*>(ptrs + base);
    const iv4* s4 = reinterpret_cast<const iv4*>(csr + base);
    #pragma unroll
    for (int q = 0; q < EPT1 / 4; ++q) {
        iv4 p = __builtin_nontemporal_load(p4 + q * BLK1 + tid);
        ps[q*4+0] = p[0]; ps[q*4+1] = p[1]; ps[q*4+2] = p[2]; ps[q*4+3] = p[3];
    }
    #pragma unroll
    for (int q = 0; q < EPT1 / 4; ++q) {
        iv4 s = __builtin_nontemporal_load(s4 + q * BLK1 + tid);
        cs[q*4+0] = s[0]; cs[q*4+1] = s[1]; cs[q*4+2] = s[2]; cs[q*4+3] = s[3];
    }
    #pragma unroll
    for (int i = 0; i < EPT1; ++i) atomicAdd(&hist[ps[i] >> RSH], 1);
    __syncthreads();
    if (tid == 0) {
        int acc = 0;
        #pragma unroll
        for (int r = 0; r < NREGS; ++r) { bounds[r] = acc; acc += hist[r]; }
        bounds[NREGS] = acc;
    }
    __syncthreads();
    if (tid < NREGS) hist[tid] = bounds[tid];
    __syncthreads();
    #pragma unroll
    for (int i = 0; i < EPT1; ++i) {
        int pp = ps[i], ss = cs[i];
        int r  = pp >> RSH;
        int sl = ss - seg_base;
        unsigned pk;
        if (sl >= 0xFFFF) {
            atomicAdd(out + ss, x[pp]);
            pk = (((unsigned)pp & 0xFFFFu) << 16) | 0xFFFFu;
        } else {
            pk = (((unsigned)pp & 0xFFFFu) << 16) | (unsigned)sl;
        }
        int pos = atomicAdd(&hist[r], 1);
        packed[pos] = pk;
    }
    __syncthreads();
    {
        const uv4* pl = reinterpret_cast<const uv4*>(packed);
        uv4* w4 = reinterpret_cast<uv4*>(wse + base);
        for (int i = tid; i < CHUNK1 / 4; i += BLK1)
            __builtin_nontemporal_store(pl[i], w4 + i);
    }
    for (int i = tid; i <= NREGS; i += BLK1)
        wsb[(size_t)c * (NREGS + 1) + i] = bounds[i];
}

__global__ __launch_bounds__(BLK2) void consume_kernel(
    const float*    __restrict__ x,
    const int*      __restrict__ csr,
    float*          __restrict__ out,
    const unsigned* __restrict__ wse,
    const int*      __restrict__ wsb,
    long long eb)
{
    __shared__ float accum[CAP];
    __shared__ int   cbnd[CPB][NREGS + 1];

    const int c = blockIdx.x, tid = threadIdx.x;
    const int w = tid >> 6, lane = tid & 63;
    const long long base = (long long)c * eb;

    for (int i = tid; i < CAP; i += BLK2) accum[i] = 0.f;
    {
        const int* src = wsb + (size_t)c * CPB * (NREGS + 1);
        for (int i = tid; i < CPB * (NREGS + 1); i += BLK2)
            (&cbnd[0][0])[i] = src[i];
    }
    const int seg_base = csr[base];
    const int seg_last = csr[base + eb - 1];
    __syncthreads();

    const long long chunk_base = base + (long long)w * CHUNK1;
    for (int r = 0; r < NREGS; ++r) {
        const int lo = cbnd[w][r], hi = cbnd[w][r + 1];
        const int rb = r << RSH;
        for (int i = lo + lane; i < hi; i += 64) {
            unsigned pk = __builtin_nontemporal_load(wse + chunk_base + i);
            float val = x[rb | (int)(pk >> 16)];
            int   sl  = (int)(pk & 0xFFFFu);
            if (sl == 0xFFFF) continue;
            if (sl < CAP) atomicAdd(&accum[sl], val);
            else          atomicAdd(out + seg_base + sl, val);
        }
    }
    __syncthreads();

    const int range = seg_last - seg_base + 1;
    const int hi = range < CAP ? range : CAP;
    for (int i = tid; i < hi; i += BLK2) {
        float v = accum[i];
        if (i == 0 || i == range - 1) {
            if (v != 0.f) atomicAdd(out + seg_base + i, v);
        } else {
            out[seg_base + i] = v;
        }
    }
}

// =================== round-5 fallback (generic sizes) ===================
#define EPT   16
#define BLK   256
#define CHUNK (BLK * EPT)
#define NREG  16
#define SW(s) ((s) ^ (((s) >> 4) & 0xF))

__global__ __launch_bounds__(BLK, 4) void seg_gather_sort_kernel(
    const float* __restrict__ x,
    const int*   __restrict__ ptrs,
    const int*   __restrict__ csr,
    float*       __restrict__ out,
    int n_edges, int rshift, int n_chunks)
{
    __shared__ int      hist[NREG];
    __shared__ int      bounds[NREG + 1];
    __shared__ unsigned packed[CHUNK];
    __shared__ float    vlds[CHUNK];

    const int tid = threadIdx.x;
    const unsigned lmask = (1u << rshift) - 1u;

    for (int c = blockIdx.x; c < n_chunks; c += gridDim.x) {
        const long long base_e = (long long)c * CHUNK;
        if (base_e + CHUNK <= n_edges) {
            const long long e0 = base_e + (long long)tid * EPT;
            const iv4* p4 = reinterpret_cast<const iv4*>(ptrs + e0);
            const iv4* c4 = reinterpret_cast<const iv4*>(csr + e0);
            int ps[EPT], cs[EPT];
            #pragma unroll
            for (int q = 0; q < EPT / 4; ++q) {
                iv4 p = __builtin_nontemporal_load(p4 + q);
                ps[q*4+0] = p[0]; ps[q*4+1] = p[1]; ps[q*4+2] = p[2]; ps[q*4+3] = p[3];
            }
            #pragma unroll
            for (int q = 0; q < EPT / 4; ++q) {
                iv4 cc = __builtin_nontemporal_load(c4 + q);
                cs[q*4+0] = cc[0]; cs[q*4+1] = cc[1]; cs[q*4+2] = cc[2]; cs[q*4+3] = cc[3];
            }
            if (tid < NREG) hist[tid] = 0;
            __syncthreads();
            #pragma unroll
            for (int i = 0; i < EPT; ++i) atomicAdd(&hist[ps[i] >> rshift], 1);
            __syncthreads();
            if (tid == 0) {
                int acc = 0; bounds[0] = 0;
                #pragma unroll
                for (int r = 0; r < NREG; ++r) { acc += hist[r]; bounds[r+1] = acc; }
                #pragma unroll
                for (int r = 0; r < NREG; ++r) hist[r] = bounds[r];
            }
            __syncthreads();
            #pragma unroll
            for (int i = 0; i < EPT; ++i) {
                int r   = ps[i] >> rshift;
                int pos = atomicAdd(&hist[r], 1);
                packed[pos] = (((unsigned)ps[i] & lmask) << 12) | (unsigned)(tid*EPT+i);
            }
            __syncthreads();
            {
                int r = 0;
                #pragma unroll
                for (int k = 0; k < EPT; ++k) {
                    int e = k * BLK + tid;
                    while (e >= bounds[r + 1]) ++r;
                    unsigned pk = packed[e];
                    int ptr  = (r << rshift) | (int)(pk >> 12);
                    int slot = (int)(pk & 0xFFFu);
                    vlds[SW(slot)] = x[ptr];
                }
            }
            __syncthreads();
            float v[EPT];
            #pragma unroll
            for (int i = 0; i < EPT; ++i) v[i] = vlds[SW(tid * EPT + i)];
            int cur = cs[0]; float sum = 0.f; bool first = true;
            #pragma unroll
            for (int i = 0; i < EPT; ++i) {
                int seg = cs[i];
                if (seg != cur) {
                    if (first) { atomicAdd(out + cur, sum); first = false; }
                    else       { out[cur] = sum; }
                    cur = seg; sum = 0.f;
                }
                sum += v[i];
            }
            atomicAdd(out + cur, sum);
            __syncthreads();
        } else {
            long long e0 = base_e + (long long)tid * EPT;
            if (e0 < n_edges) {
                long long eend = e0 + EPT; if (eend > n_edges) eend = n_edges;
                int cur = csr[e0]; float sum = 0.f; bool first = true;
                for (long long e = e0; e < eend; ++e) {
                    int seg = csr[e];
                    if (seg != cur) {
                        if (first) { atomicAdd(out + cur, sum); first = false; }
                        else       { out[cur] = sum; }
                        cur = seg; sum = 0.f;
                    }
                    sum += x[ptrs[e]];
                }
                atomicAdd(out + cur, sum);
            }
        }
    }
}

extern "C" void kernel_launch(void* const* d_in, const int* in_sizes, int n_in,
                              void* d_out, int out_size, void* d_ws, size_t ws_size,
                              hipStream_t stream) {
    const float* x    = (const float*)d_in[0];
    const int*   ptrs = (const int*)d_in[1];
    const int*   csr  = (const int*)d_in[2];
    float*       out  = (float*)d_out;

    const int n_x     = in_sizes[0];
    const int n_edges = in_sizes[2];

    // Zero base for atomics + empty segments (d_out poisoned by harness).
    (void)hipMemsetAsync(out, 0, (size_t)out_size * sizeof(float), stream);

    const long long eb = (long long)CHUNK1 * CPB;          // 131072
    const int n_chunks1 = n_edges / CHUNK1;

    // v9 layout: [wsp u16*N][wss u16*N][wsv f32*N][wsb ints]
    const size_t wsb9_off  = (size_t)n_edges * 8;
    const size_t ws_need9  = wsb9_off + (size_t)n_chunks1 * (NREGS2 + 1) * 4;
    const bool shape_ok9 = (n_edges % eb == 0) && (n_x % 4 == 0) &&
                           (n_x <= (NREGS2 << RSH2));
    // v7 layout: [wse u32*N][wsb ints]
    const size_t ws_need7 = (size_t)n_edges * 4 +
                            (size_t)n_chunks1 * (NREGS + 1) * 4;
    const bool shape_ok7 = (n_edges % eb == 0) && (n_x <= (NREGS << RSH));

    if (shape_ok9 && ws_size >= ws_need9) {
        unsigned short* wsp = (unsigned short*)d_ws;
        unsigned short* wss = (unsigned short*)d_ws + n_edges;
        float*          wsv = (float*)(void*)((char*)d_ws + (size_t)n_edges * 4);
        int*            wsb = (int*)(void*)((char*)d_ws + wsb9_off);
        const int g2 = (int)(n_edges / eb);                // 256
        sort_chunks2_kernel<<<n_chunks1, BLK1, 0, stream>>>(
            x, ptrs, csr, out, wsp, wss, wsb, eb);
        region_gather_kernel<<<NREGS2, BLK2, 0, stream>>>(
            x, wsp, wsv, wsb, n_chunks1, n_x);
        reduce_kernel<<<g2, BLK2, 0, stream>>>(
            csr, out, wss, wsv, eb);
    } else if (shape_ok7 && ws_size >= ws_need7) {
        unsigned* wse = (unsigned*)d_ws;
        int*      wsb = (int*)d_ws + n_edges;
        const int g2 = (int)(n_edges / eb);
        sort_chunks_kernel<<<n_chunks1, BLK1, 0, stream>>>(
            x, ptrs, csr, out, wse, wsb, eb);
        consume_kernel<<<g2, BLK2, 0, stream>>>(
            x, csr, out, wse, wsb, eb);
    } else {
        int rshift = 0;
        while ((1LL << rshift) < (n_x + NREG - 1) / NREG) ++rshift;
        const int n_chunks = (int)(((long long)n_edges + CHUNK - 1) / CHUNK);
        int grid = 1024; if (grid > n_chunks) grid = n_chunks;
        seg_gather_sort_kernel<<<grid, BLK, 0, stream>>>(
            x, ptrs, csr, out, n_edges, rshift, n_chunks);
    }
}

// Round 10
// 433.723 us; speedup vs baseline: 1.1684x; 1.1684x over previous
//
#include <hip/hip_runtime.h>

typedef int      iv4 __attribute__((ext_vector_type(4)));
typedef unsigned uv4 __attribute__((ext_vector_type(4)));
typedef float    fv4 __attribute__((ext_vector_type(4)));

// ======================= v10: 3-pass, all-streaming ========================
// K1: per-32K-chunk LDS counting sort by ptr-region, entries (ptr_local|orig)
// K2: per-region LDS-staged gather (bounds cached in LDS), coalesced wsv
// K3: per-chunk LDS permutation-inversion + register run-reduction
#define NREGS2  256               // x regions, 128 KB each
#define RSH2    15                // region shift
#define REGW    (1 << RSH2)       // 32768 floats per region
#define CHUNKB  32768             // edges per chunk
#define BLKB    1024
#define EPTB    32                // CHUNKB / BLKB
#define MAXC    1024              // max chunks (K2 LDS bounds cache)
#define SWZ(i)  ((i) ^ (((i) >> 5) & 31))   // LDS bank swizzle (involution)

// ---- K1: sort chunk by region; emit (ptr_local15 << 16) | orig15 ----
__global__ __launch_bounds__(BLKB) void sortbig_kernel(
    const int* __restrict__ ptrs,
    unsigned*  __restrict__ wse,   // [n_edges] packed, chunk-contiguous sorted
    int*       __restrict__ wsb)   // [n_chunks * (NREGS2+1)] per-chunk bounds
{
    __shared__ int      hist[NREGS2];
    __shared__ int      scn[NREGS2];
    __shared__ int      bounds[NREGS2 + 1];
    __shared__ unsigned packed[CHUNKB];        // 128 KB

    const int c = blockIdx.x, tid = threadIdx.x;
    const long long base = (long long)c * CHUNKB;

    if (tid < NREGS2) hist[tid] = 0;
    __syncthreads();

    // coalesced ptr loads; ps[q*4+k] is edge orig = q*4096 + tid*4 + k
    int ps[EPTB];
    const iv4* p4 = reinterpret_cast<const iv4*>(ptrs + base);
    #pragma unroll
    for (int q = 0; q < EPTB / 4; ++q) {
        iv4 p = __builtin_nontemporal_load(p4 + q * BLKB + tid);
        ps[q*4+0] = p[0]; ps[q*4+1] = p[1]; ps[q*4+2] = p[2]; ps[q*4+3] = p[3];
    }

    #pragma unroll
    for (int i = 0; i < EPTB; ++i) atomicAdd(&hist[ps[i] >> RSH2], 1);
    __syncthreads();

    // Hillis-Steele scan over 256 counts
    if (tid < NREGS2) scn[tid] = hist[tid];
    __syncthreads();
    for (int off = 1; off < NREGS2; off <<= 1) {
        int v = 0;
        if (tid < NREGS2) { v = scn[tid]; if (tid >= off) v += scn[tid - off]; }
        __syncthreads();
        if (tid < NREGS2) scn[tid] = v;
        __syncthreads();
    }
    if (tid < NREGS2) bounds[tid + 1] = scn[tid];
    if (tid == 0) bounds[0] = 0;
    __syncthreads();
    if (tid < NREGS2) hist[tid] = bounds[tid];           // cursors
    __syncthreads();

    // rank + scatter (unstable OK: K3 inverts by orig position)
    #pragma unroll
    for (int q = 0; q < EPTB / 4; ++q) {
        #pragma unroll
        for (int k = 0; k < 4; ++k) {
            int pp   = ps[q * 4 + k];
            int orig = (q << 12) + (tid << 2) + k;       // q*4096 + tid*4 + k
            int pos  = atomicAdd(&hist[pp >> RSH2], 1);
            packed[pos] = (((unsigned)pp & (REGW - 1)) << 16) | (unsigned)orig;
        }
    }
    __syncthreads();

    // coalesced write-out
    {
        const uv4* pl = reinterpret_cast<const uv4*>(packed);
        uv4* w4 = reinterpret_cast<uv4*>(wse + base);
        for (int i = tid; i < CHUNKB / 4; i += BLKB)
            __builtin_nontemporal_store(pl[i], w4 + i);
    }
    for (int i = tid; i <= NREGS2; i += BLKB)
        wsb[(size_t)c * (NREGS2 + 1) + i] = bounds[i];
}

// ---- K2: block r stages x-region r in LDS; streams all chunk slices ----
__global__ __launch_bounds__(BLKB) void region_gather2_kernel(
    const float*    __restrict__ x,
    const unsigned* __restrict__ wse,
    float*          __restrict__ wsv,
    const int*      __restrict__ wsb,
    int n_chunks, int n_x)
{
    __shared__ float xr[REGW];                 // 128 KB
    __shared__ int   blo[MAXC];                // 4 KB
    __shared__ int   bhi[MAXC];                // 4 KB

    const int r = blockIdx.x, tid = threadIdx.x;
    const int w = tid >> 6, lane = tid & 63;
    const long long rb = (long long)r << RSH2;

    // stage region (coalesced float4, clamped)
    {
        const fv4* xs = reinterpret_cast<const fv4*>(x + rb);
        fv4* xd = reinterpret_cast<fv4*>(xr);
        for (int i = tid; i < REGW / 4; i += BLKB)
            if (rb + (long long)(i + 1) * 4 <= n_x) xd[i] = xs[i];
    }
    // cache this region's bounds for ALL chunks (one-time strided loads)
    for (int c = tid; c < n_chunks; c += BLKB) {
        blo[c] = wsb[(size_t)c * (NREGS2 + 1) + r];
        bhi[c] = wsb[(size_t)c * (NREGS2 + 1) + r + 1];
    }
    __syncthreads();

    // wave w walks chunks w, w+16, ... : no global bounds loads, independent
    // iterations -> pipelines; reads & writes both slice-contiguous.
    for (int c = w; c < n_chunks; c += 16) {
        const int lo = blo[c], hi = bhi[c];
        const long long cb = (long long)c * CHUNKB;
        for (int i = lo + lane; i < hi; i += 64) {
            unsigned pk = __builtin_nontemporal_load(wse + cb + i);
            __builtin_nontemporal_store(xr[pk >> 16], wsv + cb + i);
        }
    }
}

// ---- K3: invert chunk permutation in LDS, run-reduce in original order ----
__global__ __launch_bounds__(BLKB) void invert_reduce_kernel(
    const int*      __restrict__ csr,
    float*          __restrict__ out,
    const unsigned* __restrict__ wse,
    const float*    __restrict__ wsv)
{
    __shared__ float vlds[CHUNKB];             // 128 KB

    const int c = blockIdx.x, tid = threadIdx.x;
    const long long base = (long long)c * CHUNKB;

    // phase A: stream sorted (entry, value) pairs; scatter value to its
    // original position (unique -> plain LDS writes, swizzled banks)
    {
        const uv4* e4 = reinterpret_cast<const uv4*>(wse + base);
        const fv4* v4 = reinterpret_cast<const fv4*>(wsv + base);
        for (int i = tid; i < CHUNKB / 4; i += BLKB) {
            uv4 pk = __builtin_nontemporal_load(e4 + i);
            fv4 vv = __builtin_nontemporal_load(v4 + i);
            #pragma unroll
            for (int k = 0; k < 4; ++k) {
                int o = (int)(pk[k] & 0xFFFFu);
                vlds[SWZ(o)] = vv[k];
            }
        }
    }
    __syncthreads();

    // phase B: thread t owns edges [t*32, t*32+32) in ORIGINAL order; csr is
    // sorted there -> register run-accumulation; interior runs exclusive ->
    // plain store onto zeroed out; first/last run may span threads -> atomic.
    {
        const int o0 = tid * EPTB;
        int cs[EPTB];
        const iv4* s4 = reinterpret_cast<const iv4*>(csr + base + o0);
        #pragma unroll
        for (int q = 0; q < EPTB / 4; ++q) {
            iv4 s = __builtin_nontemporal_load(s4 + q);
            cs[q*4+0] = s[0]; cs[q*4+1] = s[1]; cs[q*4+2] = s[2]; cs[q*4+3] = s[3];
        }
        int   cur   = cs[0];
        float sum   = 0.f;
        bool  first = true;
        #pragma unroll
        for (int i = 0; i < EPTB; ++i) {
            int seg = cs[i];
            if (seg != cur) {
                if (first) { atomicAdd(out + cur, sum); first = false; }
                else       { out[cur] = sum; }
                cur = seg;
                sum = 0.f;
            }
            sum += vlds[SWZ(o0 + i)];
        }
        atomicAdd(out + cur, sum);
    }
}

// =================== v7 fallback (proven, 128 regions) ======================
#define BLK1    512
#define EPT1    16
#define CHUNK1  (BLK1 * EPT1)
#define CPB     16
#define BLK2    1024
#define CAP     38400
#define NREGS   128
#define RSH     16

__global__ __launch_bounds__(BLK1) void sort_chunks_kernel(
    const float* __restrict__ x,
    const int*   __restrict__ ptrs,
    const int*   __restrict__ csr,
    float*       __restrict__ out,
    unsigned*    __restrict__ wse,
    int*         __restrict__ wsb,
    long long eb)
{
    __shared__ int      hist[NREGS];
    __shared__ int      bounds[NREGS + 1];
    __shared__ unsigned packed[CHUNK1];

    const int c = blockIdx.x, tid = threadIdx.x;
    const long long base = (long long)c * CHUNK1;
    const int cb = (int)(base / eb);
    const int seg_base = csr[(long long)cb * eb];

    if (tid < NREGS) hist[tid] = 0;
    __syncthreads();

    int ps[EPT1], cs[EPT1];
    const iv4* p4 = reinterpret_cast<const iv4*>(ptrs + base);
    const iv4* s4 = reinterpret_cast<const iv4*>(csr + base);
    #pragma unroll
    for (int q = 0; q < EPT1 / 4; ++q) {
        iv4 p = __builtin_nontemporal_load(p4 + q * BLK1 + tid);
        ps[q*4+0] = p[0]; ps[q*4+1] = p[1]; ps[q*4+2] = p[2]; ps[q*4+3] = p[3];
    }
    #pragma unroll
    for (int q = 0; q < EPT1 / 4; ++q) {
        iv4 s = __builtin_nontemporal_load(s4 + q * BLK1 + tid);
        cs[q*4+0] = s[0]; cs[q*4+1] = s[1]; cs[q*4+2] = s[2]; cs[q*4+3] = s[3];
    }
    #pragma unroll
    for (int i = 0; i < EPT1; ++i) atomicAdd(&hist[ps[i] >> RSH], 1);
    __syncthreads();
    if (tid == 0) {
        int acc = 0;
        #pragma unroll
        for (int r = 0; r < NREGS; ++r) { bounds[r] = acc; acc += hist[r]; }
        bounds[NREGS] = acc;
    }
    __syncthreads();
    if (tid < NREGS) hist[tid] = bounds[tid];
    __syncthreads();
    #pragma unroll
    for (int i = 0; i < EPT1; ++i) {
        int pp = ps[i], ss = cs[i];
        int r  = pp >> RSH;
        int sl = ss - seg_base;
        unsigned pk;
        if (sl >= 0xFFFF) {
            atomicAdd(out + ss, x[pp]);
            pk = (((unsigned)pp & 0xFFFFu) << 16) | 0xFFFFu;
        } else {
            pk = (((unsigned)pp & 0xFFFFu) << 16) | (unsigned)sl;
        }
        int pos = atomicAdd(&hist[r], 1);
        packed[pos] = pk;
    }
    __syncthreads();
    {
        const uv4* pl = reinterpret_cast<const uv4*>(packed);
        uv4* w4 = reinterpret_cast<uv4*>(wse + base);
        for (int i = tid; i < CHUNK1 / 4; i += BLK1)
            __builtin_nontemporal_store(pl[i], w4 + i);
    }
    for (int i = tid; i <= NREGS; i += BLK1)
        wsb[(size_t)c * (NREGS + 1) + i] = bounds[i];
}

__global__ __launch_bounds__(BLK2) void consume_kernel(
    const float*    __restrict__ x,
    const int*      __restrict__ csr,
    float*          __restrict__ out,
    const unsigned* __restrict__ wse,
    const int*      __restrict__ wsb,
    long long eb)
{
    __shared__ float accum[CAP];
    __shared__ int   cbnd[CPB][NREGS + 1];

    const int c = blockIdx.x, tid = threadIdx.x;
    const int w = tid >> 6, lane = tid & 63;
    const long long base = (long long)c * eb;

    for (int i = tid; i < CAP; i += BLK2) accum[i] = 0.f;
    {
        const int* src = wsb + (size_t)c * CPB * (NREGS + 1);
        for (int i = tid; i < CPB * (NREGS + 1); i += BLK2)
            (&cbnd[0][0])[i] = src[i];
    }
    const int seg_base = csr[base];
    const int seg_last = csr[base + eb - 1];
    __syncthreads();

    const long long chunk_base = base + (long long)w * CHUNK1;
    for (int r = 0; r < NREGS; ++r) {
        const int lo = cbnd[w][r], hi = cbnd[w][r + 1];
        const int rb = r << RSH;
        for (int i = lo + lane; i < hi; i += 64) {
            unsigned pk = __builtin_nontemporal_load(wse + chunk_base + i);
            float val = x[rb | (int)(pk >> 16)];
            int   sl  = (int)(pk & 0xFFFFu);
            if (sl == 0xFFFF) continue;
            if (sl < CAP) atomicAdd(&accum[sl], val);
            else          atomicAdd(out + seg_base + sl, val);
        }
    }
    __syncthreads();

    const int range = seg_last - seg_base + 1;
    const int hi = range < CAP ? range : CAP;
    for (int i = tid; i < hi; i += BLK2) {
        float v = accum[i];
        if (i == 0 || i == range - 1) {
            if (v != 0.f) atomicAdd(out + seg_base + i, v);
        } else {
            out[seg_base + i] = v;
        }
    }
}

// =================== round-5 fallback (generic sizes) ===================
#define EPT   16
#define BLK   256
#define CHUNK (BLK * EPT)
#define NREG  16
#define SW5(s) ((s) ^ (((s) >> 4) & 0xF))

__global__ __launch_bounds__(BLK, 4) void seg_gather_sort_kernel(
    const float* __restrict__ x,
    const int*   __restrict__ ptrs,
    const int*   __restrict__ csr,
    float*       __restrict__ out,
    int n_edges, int rshift, int n_chunks)
{
    __shared__ int      hist[NREG];
    __shared__ int      bounds[NREG + 1];
    __shared__ unsigned packed[CHUNK];
    __shared__ float    vlds[CHUNK];

    const int tid = threadIdx.x;
    const unsigned lmask = (1u << rshift) - 1u;

    for (int c = blockIdx.x; c < n_chunks; c += gridDim.x) {
        const long long base_e = (long long)c * CHUNK;
        if (base_e + CHUNK <= n_edges) {
            const long long e0 = base_e + (long long)tid * EPT;
            const iv4* p4 = reinterpret_cast<const iv4*>(ptrs + e0);
            const iv4* c4 = reinterpret_cast<const iv4*>(csr + e0);
            int ps[EPT], cs[EPT];
            #pragma unroll
            for (int q = 0; q < EPT / 4; ++q) {
                iv4 p = __builtin_nontemporal_load(p4 + q);
                ps[q*4+0] = p[0]; ps[q*4+1] = p[1]; ps[q*4+2] = p[2]; ps[q*4+3] = p[3];
            }
            #pragma unroll
            for (int q = 0; q < EPT / 4; ++q) {
                iv4 cc = __builtin_nontemporal_load(c4 + q);
                cs[q*4+0] = cc[0]; cs[q*4+1] = cc[1]; cs[q*4+2] = cc[2]; cs[q*4+3] = cc[3];
            }
            if (tid < NREG) hist[tid] = 0;
            __syncthreads();
            #pragma unroll
            for (int i = 0; i < EPT; ++i) atomicAdd(&hist[ps[i] >> rshift], 1);
            __syncthreads();
            if (tid == 0) {
                int acc = 0; bounds[0] = 0;
                #pragma unroll
                for (int r = 0; r < NREG; ++r) { acc += hist[r]; bounds[r+1] = acc; }
                #pragma unroll
                for (int r = 0; r < NREG; ++r) hist[r] = bounds[r];
            }
            __syncthreads();
            #pragma unroll
            for (int i = 0; i < EPT; ++i) {
                int r   = ps[i] >> rshift;
                int pos = atomicAdd(&hist[r], 1);
                packed[pos] = (((unsigned)ps[i] & lmask) << 12) | (unsigned)(tid*EPT+i);
            }
            __syncthreads();
            {
                int r = 0;
                #pragma unroll
                for (int k = 0; k < EPT; ++k) {
                    int e = k * BLK + tid;
                    while (e >= bounds[r + 1]) ++r;
                    unsigned pk = packed[e];
                    int ptr  = (r << rshift) | (int)(pk >> 12);
                    int slot = (int)(pk & 0xFFFu);
                    vlds[SW5(slot)] = x[ptr];
                }
            }
            __syncthreads();
            float v[EPT];
            #pragma unroll
            for (int i = 0; i < EPT; ++i) v[i] = vlds[SW5(tid * EPT + i)];
            int cur = cs[0]; float sum = 0.f; bool first = true;
            #pragma unroll
            for (int i = 0; i < EPT; ++i) {
                int seg = cs[i];
                if (seg != cur) {
                    if (first) { atomicAdd(out + cur, sum); first = false; }
                    else       { out[cur] = sum; }
                    cur = seg; sum = 0.f;
                }
                sum += v[i];
            }
            atomicAdd(out + cur, sum);
            __syncthreads();
        } else {
            long long e0 = base_e + (long long)tid * EPT;
            if (e0 < n_edges) {
                long long eend = e0 + EPT; if (eend > n_edges) eend = n_edges;
                int cur = csr[e0]; float sum = 0.f; bool first = true;
                for (long long e = e0; e < eend; ++e) {
                    int seg = csr[e];
                    if (seg != cur) {
                        if (first) { atomicAdd(out + cur, sum); first = false; }
                        else       { out[cur] = sum; }
                        cur = seg; sum = 0.f;
                    }
                    sum += x[ptrs[e]];
                }
                atomicAdd(out + cur, sum);
            }
        }
    }
}

extern "C" void kernel_launch(void* const* d_in, const int* in_sizes, int n_in,
                              void* d_out, int out_size, void* d_ws, size_t ws_size,
                              hipStream_t stream) {
    const float* x    = (const float*)d_in[0];
    const int*   ptrs = (const int*)d_in[1];
    const int*   csr  = (const int*)d_in[2];
    float*       out  = (float*)d_out;

    const int n_x     = in_sizes[0];
    const int n_edges = in_sizes[2];

    // Zero base for atomics + empty segments (d_out poisoned by harness).
    (void)hipMemsetAsync(out, 0, (size_t)out_size * sizeof(float), stream);

    // ---------------- v10 path ----------------
    const int n_chunksB = n_edges / CHUNKB;
    const size_t need10 = (size_t)n_edges * 8 +
                          (size_t)n_chunksB * (NREGS2 + 1) * 4;
    const bool ok10 = (n_edges % CHUNKB == 0) && (n_chunksB <= MAXC) &&
                      (n_x % 4 == 0) && (n_x <= (NREGS2 << RSH2)) &&
                      (ws_size >= need10);

    // ---------------- v7 fallback ----------------
    const long long eb7 = (long long)CHUNK1 * CPB;         // 131072
    const int n_chunks1 = n_edges / CHUNK1;
    const size_t need7 = (size_t)n_edges * 4 +
                         (size_t)n_chunks1 * (NREGS + 1) * 4;
    const bool ok7 = (n_edges % eb7 == 0) && (n_x <= (NREGS << RSH)) &&
                     (ws_size >= need7);

    if (ok10) {
        unsigned* wse = (unsigned*)d_ws;
        float*    wsv = (float*)(void*)((char*)d_ws + (size_t)n_edges * 4);
        int*      wsb = (int*)(void*)((char*)d_ws + (size_t)n_edges * 8);
        sortbig_kernel<<<n_chunksB, BLKB, 0, stream>>>(ptrs, wse, wsb);
        region_gather2_kernel<<<NREGS2, BLKB, 0, stream>>>(
            x, wse, wsv, wsb, n_chunksB, n_x);
        invert_reduce_kernel<<<n_chunksB, BLKB, 0, stream>>>(
            csr, out, wse, wsv);
    } else if (ok7) {
        unsigned* wse = (unsigned*)d_ws;
        int*      wsb = (int*)d_ws + n_edges;
        const int g2 = (int)(n_edges / eb7);
        sort_chunks_kernel<<<n_chunks1, BLK1, 0, stream>>>(
            x, ptrs, csr, out, wse, wsb, eb7);
        consume_kernel<<<g2, BLK2, 0, stream>>>(
            x, csr, out, wse, wsb, eb7);
    } else {
        int rshift = 0;
        while ((1LL << rshift) < (n_x + NREG - 1) / NREG) ++rshift;
        const int n_chunks = (int)(((long long)n_edges + CHUNK - 1) / CHUNK);
        int grid = 1024; if (grid > n_chunks) grid = n_chunks;
        seg_gather_sort_kernel<<<grid, BLK, 0, stream>>>(
            x, ptrs, csr, out, n_edges, rshift, n_chunks);
    }
}